// Round 1
// baseline (444.427 us; speedup 1.0000x reference)
//
#include <hip/hip_runtime.h>
#include <hip/hip_bf16.h>

#define NROWS 8192
#define DDIM  1024
#define BM 128
#define BN 128
#define BK 64
#define NSTRIPES 8
#define CT_PER_STRIPE 8   // 1024 cols per stripe / 128
#define MARGIN_F 0.05f

typedef __attribute__((ext_vector_type(8))) short short8;
typedef __attribute__((ext_vector_type(4))) float floatx4;

// Monotonic packing: larger sim wins; on exact tie, smaller column index wins
// (matches jnp.argmax first-occurrence semantics).
__device__ __forceinline__ unsigned long long pack_key(float v, int j) {
  unsigned int u = __float_as_uint(v);
  u = (u & 0x80000000u) ? ~u : (u | 0x80000000u);
  return ((unsigned long long)u << 32) | (unsigned long long)(0x7FFFFFFFu - (unsigned int)j);
}

// Exact fp32 pos_sim per row; also zero the atomic key array (ws is poisoned 0xAA).
__global__ void pos_kernel(const float* __restrict__ x, const float* __restrict__ y,
                           float* __restrict__ pos, unsigned long long* __restrict__ keys) {
  const int row = blockIdx.x;
  const int t = threadIdx.x;  // 256 threads, one float4 each (D=1024)
  const float4* x4 = (const float4*)(x + (size_t)row * DDIM);
  const float4* y4 = (const float4*)(y + (size_t)row * DDIM);
  float4 a = x4[t], b = y4[t];
  float s = a.x * b.x + a.y * b.y + a.z * b.z + a.w * b.w;
  for (int m = 32; m; m >>= 1) s += __shfl_down(s, m, 64);
  __shared__ float ps[4];
  if ((t & 63) == 0) ps[t >> 6] = s;
  __syncthreads();
  if (t == 0) {
    pos[row] = ps[0] + ps[1] + ps[2] + ps[3];
    keys[row] = 0ULL;
  }
}

// Fused bf16-MFMA GEMM tile + mask + row-argmax, merged globally via atomicMax.
// Block = 256 threads (4 waves, 2x2 of 64x64), tile 128x128, K staged in LDS (BK=64).
__global__ __launch_bounds__(256, 2) void mine_kernel(
    const float* __restrict__ x, const float* __restrict__ y,
    const float* __restrict__ pos, unsigned long long* __restrict__ keys) {
  __shared__ unsigned short As[BM * BK];  // [row][k] bf16, 16 KB
  __shared__ unsigned short Bs[BN * BK];  // [col][k] bf16, 16 KB
  __shared__ float pos_s[BM];

  const int t = threadIdx.x;
  const int rowBase = blockIdx.x * BM;
  const int stripe  = blockIdx.y;
  if (t < BM) pos_s[t] = pos[rowBase + t];

  const int lane = t & 63;
  const int wave = t >> 6;
  const int wr = wave & 1, wc = wave >> 1;
  const int quad = lane >> 4, l16 = lane & 15;
  const float* Ag = x + (size_t)rowBase * DDIM;

  for (int ct = 0; ct < CT_PER_STRIPE; ++ct) {
    const int colBase = stripe * (BN * CT_PER_STRIPE) + ct * BN;
    const float* Bg = y + (size_t)colBase * DDIM;

    const floatx4 zero4 = {0.f, 0.f, 0.f, 0.f};
    floatx4 acc[4][4];
#pragma unroll
    for (int mi = 0; mi < 4; ++mi)
#pragma unroll
      for (int ni = 0; ni < 4; ++ni) acc[mi][ni] = zero4;

    for (int k0 = 0; k0 < DDIM; k0 += BK) {
      __syncthreads();
      // Stage A and B tiles: 128x64 fp32 -> bf16 each. 2048 float4s per tile,
      // 8 per thread. Consecutive threads -> consecutive 16B -> coalesced.
#pragma unroll
      for (int i = 0; i < 8; ++i) {
        const int f  = t + i * 256;
        const int r  = f >> 4;          // 0..127
        const int kk = (f & 15) << 2;   // 0..60, float index within BK
        const float4 va = *(const float4*)(Ag + (size_t)r * DDIM + k0 + kk);
        const float4 vb = *(const float4*)(Bg + (size_t)r * DDIM + k0 + kk);
        __hip_bfloat162 a01 = __float22bfloat162_rn(make_float2(va.x, va.y));
        __hip_bfloat162 a23 = __float22bfloat162_rn(make_float2(va.z, va.w));
        __hip_bfloat162 b01 = __float22bfloat162_rn(make_float2(vb.x, vb.y));
        __hip_bfloat162 b23 = __float22bfloat162_rn(make_float2(vb.z, vb.w));
        uint2 ua = { *(unsigned int*)&a01, *(unsigned int*)&a23 };
        uint2 ub = { *(unsigned int*)&b01, *(unsigned int*)&b23 };
        *(uint2*)&As[r * BK + kk] = ua;
        *(uint2*)&Bs[r * BK + kk] = ub;
      }
      __syncthreads();

#pragma unroll
      for (int ks = 0; ks < 2; ++ks) {
        const int koff = ks * 32 + quad * 8;
        short8 af[4], bf[4];
#pragma unroll
        for (int mi = 0; mi < 4; ++mi)
          af[mi] = *(const short8*)&As[(64 * wr + 16 * mi + l16) * BK + koff];
#pragma unroll
        for (int ni = 0; ni < 4; ++ni)
          bf[ni] = *(const short8*)&Bs[(64 * wc + 16 * ni + l16) * BK + koff];
#pragma unroll
        for (int mi = 0; mi < 4; ++mi)
#pragma unroll
          for (int ni = 0; ni < 4; ++ni)
            acc[mi][ni] = __builtin_amdgcn_mfma_f32_16x16x32_bf16(
                af[mi], bf[ni], acc[mi][ni], 0, 0, 0);
      }
    }

    // Epilogue: mask (diag, sim > pos) then row-wise (max, argmin-index).
    // C/D layout (16x16x32 bf16, HW-verified): col = lane&15, row = quad*4 + reg.
#pragma unroll
    for (int mi = 0; mi < 4; ++mi) {
#pragma unroll
      for (int r = 0; r < 4; ++r) {
        const int row_l = 64 * wr + 16 * mi + quad * 4 + r;
        const int row_g = rowBase + row_l;
        const float p = pos_s[row_l];
        float bestv = -2.0f; int bestj = 0;
#pragma unroll
        for (int ni = 0; ni < 4; ++ni) {
          float v = acc[mi][ni][r];
          const int col_g = colBase + 64 * wc + 16 * ni + l16;
          if (col_g == row_g || v > p) v = -1.0f;
          if (v > bestv || (v == bestv && col_g < bestj)) { bestv = v; bestj = col_g; }
        }
        unsigned long long key = pack_key(bestv, bestj);
#pragma unroll
        for (int m = 1; m <= 8; m <<= 1) {
          unsigned long long o = __shfl_xor(key, m, 64);
          if (o > key) key = o;
        }
        if (l16 == 0) atomicMax(&keys[row_g], key);
      }
    }
  }
}

// Unpack winners, compute loss mean. Single block, deterministic.
__global__ void final_kernel(const float* __restrict__ x, const float* __restrict__ y,
                             const float* __restrict__ pos,
                             const unsigned long long* __restrict__ keys,
                             float* __restrict__ out) {
  const int t = threadIdx.x;  // 256
  float local = 0.f;
  for (int row = t; row < NROWS; row += 256) {
    const unsigned long long k = keys[row];
    const unsigned int vb = (unsigned int)(k >> 32);
    const unsigned int u = (vb & 0x80000000u) ? (vb & 0x7FFFFFFFu) : ~vb;
    float neg = __uint_as_float(u);
    if (neg <= -1.0f) {
      // all columns masked -> argmax = 0 -> neg_sim = x[row] . y[0]
      float s = 0.f;
      for (int d = 0; d < DDIM; ++d) s += x[(size_t)row * DDIM + d] * y[d];
      neg = s;
    }
    const float l = MARGIN_F - pos[row] + neg;
    local += l > 0.f ? l : 0.f;
  }
  for (int m = 32; m; m >>= 1) local += __shfl_down(local, m, 64);
  __shared__ float ps[4];
  if ((t & 63) == 0) ps[t >> 6] = local;
  __syncthreads();
  if (t == 0) out[0] = (ps[0] + ps[1] + ps[2] + ps[3]) * (1.0f / (float)NROWS);
}

extern "C" void kernel_launch(void* const* d_in, const int* in_sizes, int n_in,
                              void* d_out, int out_size, void* d_ws, size_t ws_size,
                              hipStream_t stream) {
  const float* x = (const float*)d_in[0];
  const float* y = (const float*)d_in[1];
  float* out = (float*)d_out;

  unsigned long long* keys = (unsigned long long*)d_ws;               // 64 KB
  float* pos = (float*)((char*)d_ws + (size_t)NROWS * 8);             // 32 KB

  pos_kernel<<<NROWS, 256, 0, stream>>>(x, y, pos, keys);
  dim3 grid(NROWS / BM, NSTRIPES);
  mine_kernel<<<grid, 256, 0, stream>>>(x, y, pos, keys);
  final_kernel<<<1, 256, 0, stream>>>(x, y, pos, keys, out);
}

// Round 2
// 266.696 us; speedup vs baseline: 1.6664x; 1.6664x over previous
//
#include <hip/hip_runtime.h>
#include <hip/hip_bf16.h>

#define NROWS 8192
#define DDIM  1024
#define BM 128
#define BN 128
#define BK 64
#define NSTRIPES 16
#define CT_PER_STRIPE 4   // 8192 / (128 * 16)
#define MARGIN_F 0.05f

typedef __attribute__((ext_vector_type(8))) short short8;
typedef __attribute__((ext_vector_type(4))) float floatx4;
typedef unsigned short ushort_t;

__device__ __forceinline__ void g2lds16(const void* g, void* l) {
  __builtin_amdgcn_global_load_lds(
      (const __attribute__((address_space(1))) void*)g,
      (__attribute__((address_space(3))) void*)l, 16, 0, 0);
}

// Monotonic packing: larger sim wins; exact tie -> smaller column index
// (matches jnp.argmax first-occurrence).
__device__ __forceinline__ unsigned long long pack_key(float v, int j) {
  unsigned int u = __float_as_uint(v);
  u = (u & 0x80000000u) ? ~u : (u | 0x80000000u);
  return ((unsigned long long)u << 32) | (unsigned long long)(0x7FFFFFFFu - (unsigned int)j);
}

// One block per row: exact fp32 pos_sim, fp32->bf16 conversion of x and y,
// and zeroing of the atomic key array (ws is poisoned 0xAA).
__global__ void prep_kernel(const float* __restrict__ x, const float* __restrict__ y,
                            ushort_t* __restrict__ xb, ushort_t* __restrict__ yb,
                            float* __restrict__ pos, unsigned long long* __restrict__ keys) {
  const int row = blockIdx.x;
  const int t = threadIdx.x;  // 256 threads, one float4 each (D=1024)
  const float4 a = ((const float4*)(x + (size_t)row * DDIM))[t];
  const float4 b = ((const float4*)(y + (size_t)row * DDIM))[t];
  float s = a.x * b.x + a.y * b.y + a.z * b.z + a.w * b.w;

  __hip_bfloat162 a01 = __float22bfloat162_rn(make_float2(a.x, a.y));
  __hip_bfloat162 a23 = __float22bfloat162_rn(make_float2(a.z, a.w));
  __hip_bfloat162 b01 = __float22bfloat162_rn(make_float2(b.x, b.y));
  __hip_bfloat162 b23 = __float22bfloat162_rn(make_float2(b.z, b.w));
  uint2 ua = { *(unsigned int*)&a01, *(unsigned int*)&a23 };
  uint2 ub = { *(unsigned int*)&b01, *(unsigned int*)&b23 };
  ((uint2*)(xb + (size_t)row * DDIM))[t] = ua;
  ((uint2*)(yb + (size_t)row * DDIM))[t] = ub;

  for (int m = 32; m; m >>= 1) s += __shfl_down(s, m, 64);
  __shared__ float ps[4];
  if ((t & 63) == 0) ps[t >> 6] = s;
  __syncthreads();
  if (t == 0) {
    pos[row] = ps[0] + ps[1] + ps[2] + ps[3];
    keys[row] = 0ULL;
  }
}

// bf16 MFMA GEMM tile (m97-style global_load_lds staging, XOR-swizzled LDS)
// fused with mask + row-argmax, merged globally via atomicMax.
// LDS row = 64 bf16 = 8 chunks of 16B; chunk c of row r stored at c^(r&7):
// fragment-read phase (16 lanes, consecutive rows) then spans 8 distinct bank
// quads (2-way aliasing only, which is free per m136).
__global__ __launch_bounds__(256, 4) void mine_kernel(
    const ushort_t* __restrict__ xb, const ushort_t* __restrict__ yb,
    const float* __restrict__ pos, unsigned long long* __restrict__ keys) {
  __shared__ ushort_t As[BM * BK];  // 16 KB, swizzled
  __shared__ ushort_t Bs[BN * BK];  // 16 KB, swizzled
  __shared__ float pos_s[BM];

  const int t = threadIdx.x;
  const int rowBase = blockIdx.x * BM;
  const int stripe  = blockIdx.y;
  if (t < BM) pos_s[t] = pos[rowBase + t];

  const int lane = t & 63;
  const int wave = t >> 6;
  const int wr = wave & 1, wc = wave >> 1;
  const int quad = lane >> 4, l16 = lane & 15;

  for (int ct = 0; ct < CT_PER_STRIPE; ++ct) {
    const int colBase = stripe * (BN * CT_PER_STRIPE) + ct * BN;

    const floatx4 zero4 = {0.f, 0.f, 0.f, 0.f};
    floatx4 acc[4][4];
#pragma unroll
    for (int mi = 0; mi < 4; ++mi)
#pragma unroll
      for (int ni = 0; ni < 4; ++ni) acc[mi][ni] = zero4;

    for (int k0 = 0; k0 < DDIM; k0 += BK) {
      __syncthreads();  // previous iteration's ds_reads done before overwrite
      // Stage A and B tiles via global_load_lds width=16.
      // 1024 chunks (16B) per tile; 4 issues per thread per tile.
      // LDS dest is wave-uniform base + lane*16 (HW rule) -> the per-lane
      // global address carries the swizzle.
#pragma unroll
      for (int i = 0; i < 4; ++i) {
        const int c  = i * 256 + t;          // chunk id this lane fills
        const int r  = c >> 3;               // tile row 0..127
        const int sw = (c & 7) ^ (r & 7);    // swizzled source chunk in row
        const ushort_t* gA = xb + (size_t)(rowBase + r) * DDIM + k0 + sw * 8;
        const ushort_t* gB = yb + (size_t)(colBase + r) * DDIM + k0 + sw * 8;
        ushort_t* lA = &As[(size_t)(i * 256 + wave * 64) * 8];
        ushort_t* lB = &Bs[(size_t)(i * 256 + wave * 64) * 8];
        g2lds16(gA, lA);
        g2lds16(gB, lB);
      }
      __syncthreads();  // compiler drains vmcnt(0) before s_barrier

#pragma unroll
      for (int ks = 0; ks < 2; ++ks) {
        short8 af[4], bf[4];
#pragma unroll
        for (int mi = 0; mi < 4; ++mi) {
          const int rA = 64 * wr + 16 * mi + l16;
          af[mi] = *(const short8*)&As[rA * BK + (((ks << 2) + quad) ^ (rA & 7)) * 8];
        }
#pragma unroll
        for (int ni = 0; ni < 4; ++ni) {
          const int rB = 64 * wc + 16 * ni + l16;
          bf[ni] = *(const short8*)&Bs[rB * BK + (((ks << 2) + quad) ^ (rB & 7)) * 8];
        }
#pragma unroll
        for (int mi = 0; mi < 4; ++mi)
#pragma unroll
          for (int ni = 0; ni < 4; ++ni)
            acc[mi][ni] = __builtin_amdgcn_mfma_f32_16x16x32_bf16(
                af[mi], bf[ni], acc[mi][ni], 0, 0, 0);
      }
    }

    // Epilogue: mask (diag, sim > pos), row-wise (max, min-index) reduce.
    // C/D layout (16x16x32 bf16): col = lane&15, row = quad*4 + reg.
#pragma unroll
    for (int mi = 0; mi < 4; ++mi) {
#pragma unroll
      for (int r = 0; r < 4; ++r) {
        const int row_l = 64 * wr + 16 * mi + quad * 4 + r;
        const int row_g = rowBase + row_l;
        const float p = pos_s[row_l];
        float bestv = -2.0f; int bestj = 0;
#pragma unroll
        for (int ni = 0; ni < 4; ++ni) {
          float v = acc[mi][ni][r];
          const int col_g = colBase + 64 * wc + 16 * ni + l16;
          if (col_g == row_g || v > p) v = -1.0f;
          if (v > bestv || (v == bestv && col_g < bestj)) { bestv = v; bestj = col_g; }
        }
        unsigned long long key = pack_key(bestv, bestj);
#pragma unroll
        for (int m = 1; m <= 8; m <<= 1) {
          unsigned long long o = __shfl_xor(key, m, 64);
          if (o > key) key = o;
        }
        if (l16 == 0) atomicMax(&keys[row_g], key);
      }
    }
  }
}

// Unpack winners, compute loss mean. Single block, deterministic.
__global__ void final_kernel(const float* __restrict__ x, const float* __restrict__ y,
                             const float* __restrict__ pos,
                             const unsigned long long* __restrict__ keys,
                             float* __restrict__ out) {
  const int t = threadIdx.x;  // 256
  float local = 0.f;
  for (int row = t; row < NROWS; row += 256) {
    const unsigned long long k = keys[row];
    const unsigned int vb = (unsigned int)(k >> 32);
    const unsigned int u = (vb & 0x80000000u) ? (vb & 0x7FFFFFFFu) : ~vb;
    float neg = __uint_as_float(u);
    if (neg <= -1.0f) {
      // all columns masked -> argmax = 0 -> neg_sim = x[row] . y[0]
      float s = 0.f;
      for (int d = 0; d < DDIM; ++d) s += x[(size_t)row * DDIM + d] * y[d];
      neg = s;
    }
    const float l = MARGIN_F - pos[row] + neg;
    local += l > 0.f ? l : 0.f;
  }
  for (int m = 32; m; m >>= 1) local += __shfl_down(local, m, 64);
  __shared__ float ps[4];
  if ((t & 63) == 0) ps[t >> 6] = local;
  __syncthreads();
  if (t == 0) out[0] = (ps[0] + ps[1] + ps[2] + ps[3]) * (1.0f / (float)NROWS);
}

extern "C" void kernel_launch(void* const* d_in, const int* in_sizes, int n_in,
                              void* d_out, int out_size, void* d_ws, size_t ws_size,
                              hipStream_t stream) {
  const float* x = (const float*)d_in[0];
  const float* y = (const float*)d_in[1];
  float* out = (float*)d_out;

  // ws layout: keys 64 KB | pos 32 KB | xb 16 MB | yb 16 MB  (~33.1 MB)
  unsigned long long* keys = (unsigned long long*)d_ws;
  float* pos = (float*)((char*)d_ws + (size_t)NROWS * 8);
  ushort_t* xb = (ushort_t*)((char*)d_ws + (size_t)NROWS * 8 + (size_t)NROWS * 4);
  ushort_t* yb = xb + (size_t)NROWS * DDIM;

  prep_kernel<<<NROWS, 256, 0, stream>>>(x, y, xb, yb, pos, keys);
  dim3 grid(NROWS / BM, NSTRIPES);
  mine_kernel<<<grid, 256, 0, stream>>>(xb, yb, pos, keys);
  final_kernel<<<1, 256, 0, stream>>>(x, y, pos, keys, out);
}